// Round 6
// baseline (831.496 us; speedup 1.0000x reference)
//
#include <hip/hip_runtime.h>
#include <hip/hip_bf16.h>
#include <math.h>

#define NN 512   // hidden states
#define MM 256   // timesteps / emission symbols
#define BB 128   // batch

#define KC_LDS 9           // K-chunks resident in LDS (of 16)
#define KC_REG (16 - KC_LDS)

typedef float        f32x4 __attribute__((ext_vector_type(4)));
typedef unsigned int u32;
typedef u32          u32x2 __attribute__((ext_vector_type(2)));
typedef unsigned long long u64;

__device__ __forceinline__ float wave_max(float v) {
#pragma unroll
    for (int o = 32; o > 0; o >>= 1) v = fmaxf(v, __shfl_xor(v, o));
    return v;
}
__device__ __forceinline__ float wave_sum(float v) {
#pragma unroll
    for (int o = 32; o > 0; o >>= 1) v += __shfl_xor(v, o);
    return v;
}

// ---------------- preprocessing ----------------

// Column-wise logsumexp of T (log_softmax axis=0 denominator). grid 8 x 64.
__global__ void k_col_lse(const float* __restrict__ T, float* __restrict__ c) {
    int k = blockIdx.x * 64 + threadIdx.x;
    float m = -INFINITY, s = 0.f;
    for (int i = 0; i < NN; ++i) {
        float x = T[i * NN + k];
        if (x > m) { s = s * __expf(m - x) + 1.f; m = x; }
        else       { s += __expf(x - m); }
    }
    c[k] = m + __logf(s);
}

// log-softmax of priors. grid 1 x 512.
__global__ void k_priors(const float* __restrict__ pr, float* __restrict__ lp) {
    __shared__ float red[8];
    int i = threadIdx.x;
    float x = pr[i];
    float wm = wave_max(x);
    if ((i & 63) == 0) red[i >> 6] = wm;
    __syncthreads();
    float m = red[0];
#pragma unroll
    for (int j = 1; j < 8; ++j) m = fmaxf(m, red[j]);
    float e = __expf(x - m);
    float ws = wave_sum(e);
    __syncthreads();
    if ((i & 63) == 0) red[i >> 6] = ws;
    __syncthreads();
    float S = red[0];
#pragma unroll
    for (int j = 1; j < 8; ++j) S += red[j];
    lp[i] = x - (m + __logf(S));
}

// Row max: M[i] = max_k(T[i,k]-c[k]) - log(64). grid 512 x 64.
__global__ void k_rowM(const float* __restrict__ T, const float* __restrict__ c,
                       float* __restrict__ M) {
    int i = blockIdx.x, j = threadIdx.x;
    float mx = -INFINITY;
#pragma unroll
    for (int d = 0; d < 8; ++d) {
        int k = j * 8 + d;
        mx = fmaxf(mx, T[i * NN + k] - c[k]);
    }
    mx = wave_max(mx);
    if (j == 0) M[i] = mx - __logf(64.f);
}

// Pack P into fp8 MFMA A-fragments, scaled x64 (row max -> 64).
// Fragment (tile,kc): lane l holds 8 bytes = P[row=tile*16+(l&15),
// k=kc*32+(l>>4)*8+j], j ascending. Stored as u64 at PA8[(tile*16+kc)*64+l].
// grid 512 (=tile*16+kc) x 64.
__global__ void k_packA(const float* __restrict__ T, const float* __restrict__ c,
                        const float* __restrict__ M, u32* __restrict__ PA) {
    int blk = blockIdx.x, l = threadIdx.x;
    int tile = blk >> 4, kc = blk & 15;
    int row = tile * 16 + (l & 15);
    int kb  = kc * 32 + (l >> 4) * 8;
    float Mi = M[row];                    // = rowmax - log64
    float p[8];
#pragma unroll
    for (int j = 0; j < 8; ++j)
        p[j] = __expf(T[row * NN + kb + j] - c[kb + j] - Mi);   // <= 64
    int d0 = 0, d1 = 0;
    d0 = __builtin_amdgcn_cvt_pk_fp8_f32(p[0], p[1], d0, false);
    d0 = __builtin_amdgcn_cvt_pk_fp8_f32(p[2], p[3], d0, true);
    d1 = __builtin_amdgcn_cvt_pk_fp8_f32(p[4], p[5], d1, false);
    d1 = __builtin_amdgcn_cvt_pk_fp8_f32(p[6], p[7], d1, true);
    u32x2 st = { (u32)d0, (u32)d1 };
    *(u32x2*)(PA + ((size_t)blk * 64 + l) * 2) = st;
}

// Row i of E: log-softmax, store transposed EtT[m*NN+i]. grid 512 x 64.
__global__ void k_rowE(const float* __restrict__ E, float* __restrict__ EtT) {
    int i = blockIdx.x, j = threadIdx.x;
    float v[4];
    float mx = -INFINITY;
#pragma unroll
    for (int d = 0; d < 4; ++d) {
        v[d] = E[i * MM + j * 4 + d];
        mx = fmaxf(mx, v[d]);
    }
    mx = wave_max(mx);
    float s = 0.f;
#pragma unroll
    for (int d = 0; d < 4; ++d) s += __expf(v[d] - mx);
    s = wave_sum(s);
    float lse = mx + __logf(s);
#pragma unroll
    for (int d = 0; d < 4; ++d) EtT[(size_t)(j * 4 + d) * NN + i] = v[d] - lse;
}

// ---------------- the scan (MFMA, LDS-resident P) ----------------
// One block per batch, 512 threads = 8 waves. Wave w owns i-tiles w*4..w*4+3.
// P fp8 A-frags: KC_LDS k-chunks staged ONCE into LDS (144 KB, read via
// ds_read_b64 each step — no global traffic), KC_REG chunks in VGPRs.
// u (fp8, 512B) in LDS; B = u * ones^T -> k-permutation invariant.
__global__ __launch_bounds__(512, 2) void k_scan(
        const int* __restrict__ obs, const float* __restrict__ lp,
        const float* __restrict__ M, const u32* __restrict__ PAu,
        const float* __restrict__ EtT, float* __restrict__ out) {
    int b = blockIdx.x, tid = threadIdx.x;
    int w = tid >> 6, l = tid & 63;
    int hi16 = l >> 4;                    // 0..3
    int r4 = hi16 * 4;                    // row group within a 16-row tile
    __shared__ u64 ldsA[KC_LDS * 32 * 64] __attribute__((aligned(16)));  // 144 KB
    __shared__ unsigned char us8[2][NN] __attribute__((aligned(8)));
    __shared__ float rA[8], rB[8];
    __shared__ int obs_s[MM];
    if (tid < MM) obs_s[tid] = obs[b * MM + tid];

    const u64* PA8 = (const u64*)PAu;

    // --- stage LDS-resident A-fragments: kc 0..KC_LDS-1, all 32 tiles ---
    for (int f = w; f < KC_LDS * 32; f += 8) {
        int kc = f % KC_LDS, tile = f / KC_LDS;
        ldsA[((size_t)kc * 32 + tile) * 64 + l] =
            PA8[((size_t)(tile * 16 + kc)) * 64 + l];
    }

    // --- register-resident A-fragments: kc KC_LDS..15, this wave's 4 tiles ---
    u64 pa[4][KC_REG];
#pragma unroll
    for (int ti = 0; ti < 4; ++ti)
#pragma unroll
        for (int kq = 0; kq < KC_REG; ++kq)
            pa[ti][kq] = PA8[((size_t)((w * 4 + ti) * 16 + KC_LDS + kq)) * 64 + l];

    // --- per-lane constants in C/D layout: rows (w*4+ti)*16 + r4 + r ---
    f32x4 Mi[4], emv[4], emn[4];
#pragma unroll
    for (int ti = 0; ti < 4; ++ti)
        Mi[ti] = *(const f32x4*)(M + (w * 4 + ti) * 16 + r4);

    __syncthreads();                      // obs_s + ldsA ready
    int o0 = obs_s[0];
#pragma unroll
    for (int ti = 0; ti < 4; ++ti) {
        f32x4 lpv = *(const f32x4*)(lp + (w * 4 + ti) * 16 + r4);
        emv[ti] = *(const f32x4*)(EtT + (size_t)o0 * NN + (w * 4 + ti) * 16 + r4)
                + lpv;                    // t=0: g = em0 + log_priors
    }

    const u64* Aw = ldsA + (size_t)w * 4 * 64 + l;   // + kc*2048 + ti*64

    float L = 0.f;
    int cur = 0;

#pragma unroll 1
    for (int t = 0; t < MM; ++t) {
        // PIN the small register-resident part each iteration.
#pragma unroll
        for (int ti = 0; ti < 4; ++ti)
#pragma unroll
            for (int kq = 0; kq < KC_REG; ++kq)
                asm volatile("" : "+v"(pa[ti][kq]));

        // prefetch next emission row (independent of u)
        if (t + 1 < MM) {
            int on = obs_s[t + 1];
#pragma unroll
            for (int ti = 0; ti < 4; ++ti)
                emn[ti] = *(const f32x4*)(EtT + (size_t)on * NN + (w * 4 + ti) * 16 + r4);
        }

        f32x4 g[4];
        if (t == 0) {
#pragma unroll
            for (int ti = 0; ti < 4; ++ti) g[ti] = emv[ti];
        } else {
            f32x4 acc0 = {0.f,0.f,0.f,0.f}, acc1 = {0.f,0.f,0.f,0.f};
            f32x4 acc2 = {0.f,0.f,0.f,0.f}, acc3 = {0.f,0.f,0.f,0.f};
            const unsigned char* ub = us8[cur];
#pragma unroll
            for (int kc = 0; kc < KC_LDS; ++kc) {
                u64 bb = *(const u64*)(ub + kc * 32 + hi16 * 8);  // broadcast
                u64 a0 = Aw[kc * 2048 + 0 * 64];
                u64 a1 = Aw[kc * 2048 + 1 * 64];
                u64 a2 = Aw[kc * 2048 + 2 * 64];
                u64 a3 = Aw[kc * 2048 + 3 * 64];
                acc0 = __builtin_amdgcn_mfma_f32_16x16x32_fp8_fp8((long)a0, (long)bb, acc0, 0, 0, 0);
                acc1 = __builtin_amdgcn_mfma_f32_16x16x32_fp8_fp8((long)a1, (long)bb, acc1, 0, 0, 0);
                acc2 = __builtin_amdgcn_mfma_f32_16x16x32_fp8_fp8((long)a2, (long)bb, acc2, 0, 0, 0);
                acc3 = __builtin_amdgcn_mfma_f32_16x16x32_fp8_fp8((long)a3, (long)bb, acc3, 0, 0, 0);
            }
#pragma unroll
            for (int kq = 0; kq < KC_REG; ++kq) {
                u64 bb = *(const u64*)(ub + (KC_LDS + kq) * 32 + hi16 * 8);
                acc0 = __builtin_amdgcn_mfma_f32_16x16x32_fp8_fp8((long)pa[0][kq], (long)bb, acc0, 0, 0, 0);
                acc1 = __builtin_amdgcn_mfma_f32_16x16x32_fp8_fp8((long)pa[1][kq], (long)bb, acc1, 0, 0, 0);
                acc2 = __builtin_amdgcn_mfma_f32_16x16x32_fp8_fp8((long)pa[2][kq], (long)bb, acc2, 0, 0, 0);
                acc3 = __builtin_amdgcn_mfma_f32_16x16x32_fp8_fp8((long)pa[3][kq], (long)bb, acc3, 0, 0, 0);
            }
            f32x4 sacc[4] = { acc0, acc1, acc2, acc3 };
#pragma unroll
            for (int ti = 0; ti < 4; ++ti)
#pragma unroll
                for (int r = 0; r < 4; ++r)
                    g[ti][r] = emv[ti][r] + Mi[ti][r] + __logf(sacc[ti][r]);
        }

        // --- per-step exact max (keeps fp8 u centered: max e == 1) ---
        float mx = -INFINITY;
#pragma unroll
        for (int ti = 0; ti < 4; ++ti)
#pragma unroll
            for (int r = 0; r < 4; ++r) mx = fmaxf(mx, g[ti][r]);
        mx = wave_max(mx);
        if (l == 0) rA[w] = mx;
        __syncthreads();                  // B1
        float mxt = rA[0];
#pragma unroll
        for (int j = 1; j < 8; ++j) mxt = fmaxf(mxt, rA[j]);

        int nxt = cur ^ 1;
        f32x4 ev[4];
        float loc = 0.f;
#pragma unroll
        for (int ti = 0; ti < 4; ++ti) {
#pragma unroll
            for (int r = 0; r < 4; ++r) {
                float e = __expf(g[ti][r] - mxt);   // <= 1
                ev[ti][r] = e;
                loc += e;
            }
        }
        float ws = wave_sum(loc);         // 16x duplicated across cols
        if (l == 0) rB[w] = ws;
        if ((l & 15) == 0) {              // cols duplicate -> one writer per row-group
#pragma unroll
            for (int ti = 0; ti < 4; ++ti) {
                int d = 0;
                d = __builtin_amdgcn_cvt_pk_fp8_f32(ev[ti][0], ev[ti][1], d, false);
                d = __builtin_amdgcn_cvt_pk_fp8_f32(ev[ti][2], ev[ti][3], d, true);
                *(u32*)&us8[nxt][(w * 4 + ti) * 16 + r4] = (u32)d;
            }
        }
        __syncthreads();                  // B2: rB + us8[nxt] ready
        float S = rB[0];
#pragma unroll
        for (int j = 1; j < 8; ++j) S += rB[j];
        S *= (1.f / 16.f);                // undo col duplication
        L += mxt;
        if (tid == 0) out[(size_t)b * MM + t] = L + __logf(S);
#pragma unroll
        for (int ti = 0; ti < 4; ++ti) emv[ti] = emn[ti];
        cur = nxt;
    }
}

extern "C" void kernel_launch(void* const* d_in, const int* in_sizes, int n_in,
                              void* d_out, int out_size, void* d_ws, size_t ws_size,
                              hipStream_t stream) {
    const int*   obs = (const int*)d_in[0];
    const float* pri = (const float*)d_in[1];
    const float* T   = (const float*)d_in[2];
    const float* E   = (const float*)d_in[3];
    float* out = (float*)d_out;
    char* ws = (char*)d_ws;

    float* c   = (float*)(ws + 0);
    float* lp  = (float*)(ws + 2048);
    float* M   = (float*)(ws + 4096);
    u32*   PA  = (u32*)(ws + 8192);                       // 256 KB fp8 A-frags
    float* EtT = (float*)(ws + 8192 + 256 * 1024);        // 512 KB

    k_col_lse<<<8,   64, 0, stream>>>(T, c);
    k_priors <<<1,  512, 0, stream>>>(pri, lp);
    k_rowM   <<<512, 64, 0, stream>>>(T, c, M);
    k_packA  <<<512, 64, 0, stream>>>(T, c, M, PA);
    k_rowE   <<<512, 64, 0, stream>>>(E, EtT);
    k_scan   <<<BB, 512, 0, stream>>>(obs, lp, M, PA, EtT, out);
}

// Round 7
// 493.810 us; speedup vs baseline: 1.6838x; 1.6838x over previous
//
#include <hip/hip_runtime.h>
#include <hip/hip_bf16.h>
#include <math.h>

#define NN 512   // hidden states
#define MM 256   // timesteps / emission symbols
#define BB 128   // batch

typedef float        f32x4 __attribute__((ext_vector_type(4)));
typedef unsigned int u32;
typedef u32          u32x2 __attribute__((ext_vector_type(2)));
typedef unsigned long long u64;

__device__ __forceinline__ float wave_max(float v) {
#pragma unroll
    for (int o = 32; o > 0; o >>= 1) v = fmaxf(v, __shfl_xor(v, o));
    return v;
}
__device__ __forceinline__ float wave_sum(float v) {
#pragma unroll
    for (int o = 32; o > 0; o >>= 1) v += __shfl_xor(v, o);
    return v;
}

// ---------------- preprocessing ----------------

// Column-wise logsumexp of T (log_softmax axis=0 denominator). grid 8 x 64.
__global__ void k_col_lse(const float* __restrict__ T, float* __restrict__ c) {
    int k = blockIdx.x * 64 + threadIdx.x;
    float m = -INFINITY, s = 0.f;
    for (int i = 0; i < NN; ++i) {
        float x = T[i * NN + k];
        if (x > m) { s = s * __expf(m - x) + 1.f; m = x; }
        else       { s += __expf(x - m); }
    }
    c[k] = m + __logf(s);
}

// log-softmax of priors. grid 1 x 512.
__global__ void k_priors(const float* __restrict__ pr, float* __restrict__ lp) {
    __shared__ float red[8];
    int i = threadIdx.x;
    float x = pr[i];
    float wm = wave_max(x);
    if ((i & 63) == 0) red[i >> 6] = wm;
    __syncthreads();
    float m = red[0];
#pragma unroll
    for (int j = 1; j < 8; ++j) m = fmaxf(m, red[j]);
    float e = __expf(x - m);
    float ws = wave_sum(e);
    __syncthreads();
    if ((i & 63) == 0) red[i >> 6] = ws;
    __syncthreads();
    float S = red[0];
#pragma unroll
    for (int j = 1; j < 8; ++j) S += red[j];
    lp[i] = x - (m + __logf(S));
}

// Row max: M[i] = max_k(T[i,k]-c[k]) - log(64). grid 512 x 64.
__global__ void k_rowM(const float* __restrict__ T, const float* __restrict__ c,
                       float* __restrict__ M) {
    int i = blockIdx.x, j = threadIdx.x;
    float mx = -INFINITY;
#pragma unroll
    for (int d = 0; d < 8; ++d) {
        int k = j * 8 + d;
        mx = fmaxf(mx, T[i * NN + k] - c[k]);
    }
    mx = wave_max(mx);
    if (j == 0) M[i] = mx - __logf(64.f);
}

// Pack P into fp8 MFMA A-fragments, scaled x64 (row max -> 64).
// Fragment (tile,kc): lane l holds 8 bytes = P[row=tile*16+(l&15),
// k=kc*32+(l>>4)*8+j], j ascending. Stored as u64 at PA8[(tile*16+kc)*64+l].
__global__ void k_packA(const float* __restrict__ T, const float* __restrict__ c,
                        const float* __restrict__ M, u32* __restrict__ PA) {
    int blk = blockIdx.x, l = threadIdx.x;
    int tile = blk >> 4, kc = blk & 15;
    int row = tile * 16 + (l & 15);
    int kb  = kc * 32 + (l >> 4) * 8;
    float Mi = M[row];                    // = rowmax - log64
    float p[8];
#pragma unroll
    for (int j = 0; j < 8; ++j)
        p[j] = __expf(T[row * NN + kb + j] - c[kb + j] - Mi);   // <= 64
    int d0 = 0, d1 = 0;
    d0 = __builtin_amdgcn_cvt_pk_fp8_f32(p[0], p[1], d0, false);
    d0 = __builtin_amdgcn_cvt_pk_fp8_f32(p[2], p[3], d0, true);
    d1 = __builtin_amdgcn_cvt_pk_fp8_f32(p[4], p[5], d1, false);
    d1 = __builtin_amdgcn_cvt_pk_fp8_f32(p[6], p[7], d1, true);
    u32x2 st = { (u32)d0, (u32)d1 };
    *(u32x2*)(PA + ((size_t)blk * 64 + l) * 2) = st;
}

// Row i of E: log-softmax, store transposed EtT[m*NN+i]. grid 512 x 64.
__global__ void k_rowE(const float* __restrict__ E, float* __restrict__ EtT) {
    int i = blockIdx.x, j = threadIdx.x;
    float v[4];
    float mx = -INFINITY;
#pragma unroll
    for (int d = 0; d < 4; ++d) {
        v[d] = E[i * MM + j * 4 + d];
        mx = fmaxf(mx, v[d]);
    }
    mx = wave_max(mx);
    float s = 0.f;
#pragma unroll
    for (int d = 0; d < 4; ++d) s += __expf(v[d] - mx);
    s = wave_sum(s);
    float lse = mx + __logf(s);
#pragma unroll
    for (int d = 0; d < 4; ++d) EtT[(size_t)(j * 4 + d) * NN + i] = v[d] - lse;
}

// ---------------- the scan (MFMA, S-centered epilogue) ----------------
// One block per batch, 512 threads = 8 waves. Wave w owns i-tiles w*4..w*4+3.
// P fp8 A-frags resident in AGPR/VGPR (r4 pattern). u fp8 with sum(u)=64
// (S-centering: max u >= 1/8, no per-step max reduction, no per-row log).
// e_i = exp(em_i + M_i - C_M - log4096) * s_raw_i  (<= 1 by construction);
// K_t = K_{t-1} + C_M + log64 + logS_{t-1};  out_t = K_t + logS_t.
__global__ __launch_bounds__(512, 2) void k_scan(
        const int* __restrict__ obs, const float* __restrict__ lp,
        const float* __restrict__ M, const u32* __restrict__ PAu,
        const float* __restrict__ EtT, float* __restrict__ out) {
    int b = blockIdx.x, tid = threadIdx.x;
    int w = tid >> 6, l = tid & 63;
    int hi16 = l >> 4;                    // 0..3
    int r4 = hi16 * 4;                    // row group within a 16-row tile
    __shared__ unsigned char us8[2][NN] __attribute__((aligned(8)));
    __shared__ float rA[8], rB[8];
    __shared__ int obs_s[MM];
    if (tid < MM) obs_s[tid] = obs[b * MM + tid];

    // --- stage A-fragments: 64 x u64 per lane (4 tiles x 16 k-chunks) ---
    const u64* PA8 = (const u64*)PAu;
    u64 pa[64];
#pragma unroll
    for (int ti = 0; ti < 4; ++ti)
#pragma unroll
        for (int kc = 0; kc < 16; ++kc)
            pa[ti * 16 + kc] = PA8[(size_t)(((w * 4 + ti) * 16 + kc)) * 64 + l];
#pragma unroll
    for (int q = 0; q < 64; ++q) asm volatile("" : "+v"(pa[q]));

    // --- per-lane constants in C/D layout: rows (w*4+ti)*16 + r4 + r ---
    f32x4 Mi[4];
#pragma unroll
    for (int ti = 0; ti < 4; ++ti)
        Mi[ti] = *(const f32x4*)(M + (w * 4 + ti) * 16 + r4);

    // C_M = max_i M[i]  (dup-aware: rows duplicate across l&15)
    float mloc = -INFINITY;
#pragma unroll
    for (int ti = 0; ti < 4; ++ti)
#pragma unroll
        for (int r = 0; r < 4; ++r) mloc = fmaxf(mloc, Mi[ti][r]);
    mloc = fmaxf(mloc, __shfl_xor(mloc, 16));
    mloc = fmaxf(mloc, __shfl_xor(mloc, 32));
    if (l == 0) rA[w] = mloc;
    __syncthreads();                      // rA + obs_s ready
    float C_M = rA[0];
#pragma unroll
    for (int j = 1; j < 8; ++j) C_M = fmaxf(C_M, rA[j]);

    const float LOG64   = 4.1588830833596715f;
    const float LOG4096 = 8.317766166719343f;
    float CK = C_M + LOG64;               // per-step K increment base
    f32x4 MiW[4];                         // Mi - (C_M + log4096)
#pragma unroll
    for (int ti = 0; ti < 4; ++ti) MiW[ti] = Mi[ti] - (C_M + LOG4096);

    // ---- t = 0: e = exp(em0 + log_priors) (<= 1), u = 64 e / S ----
    int o0 = obs_s[0];
    f32x4 e4[4];
    float loc = 0.f;
#pragma unroll
    for (int ti = 0; ti < 4; ++ti) {
        f32x4 em  = *(const f32x4*)(EtT + (size_t)o0 * NN + (w * 4 + ti) * 16 + r4);
        f32x4 lpv = *(const f32x4*)(lp + (w * 4 + ti) * 16 + r4);
#pragma unroll
        for (int r = 0; r < 4; ++r) {
            float e = __expf(em[r] + lpv[r]);
            e4[ti][r] = e; loc += e;
        }
    }
    loc += __shfl_xor(loc, 16);
    loc += __shfl_xor(loc, 32);
    if (l == 0) rB[w] = loc;
    __syncthreads();
    float S = rB[0];
#pragma unroll
    for (int j = 1; j < 8; ++j) S += rB[j];
    float lS = __logf(S);
    float K = 0.f;
    if (tid == 0) out[(size_t)b * MM + 0] = lS;
    float sc = 64.f / S;
    if ((l & 15) == 0) {
#pragma unroll
        for (int ti = 0; ti < 4; ++ti) {
            int d = 0;
            d = __builtin_amdgcn_cvt_pk_fp8_f32(e4[ti][0] * sc, e4[ti][1] * sc, d, false);
            d = __builtin_amdgcn_cvt_pk_fp8_f32(e4[ti][2] * sc, e4[ti][3] * sc, d, true);
            *(u32*)&us8[0][(w * 4 + ti) * 16 + r4] = (u32)d;
        }
    }
    __syncthreads();                      // us8[0] ready

    // ---- main scan ----
#pragma unroll 1
    for (int t = 1; t < MM; ++t) {
        // issue emission loads early; they complete under the MFMA loop
        int o = obs_s[t];
        f32x4 em[4];
#pragma unroll
        for (int ti = 0; ti < 4; ++ti)
            em[ti] = *(const f32x4*)(EtT + (size_t)o * NN + (w * 4 + ti) * 16 + r4);

        const unsigned char* ub = us8[(t - 1) & 1];
        f32x4 acc0 = {0.f,0.f,0.f,0.f}, acc1 = {0.f,0.f,0.f,0.f};
        f32x4 acc2 = {0.f,0.f,0.f,0.f}, acc3 = {0.f,0.f,0.f,0.f};
#pragma unroll
        for (int kc = 0; kc < 16; ++kc) {
            u64 bb = *(const u64*)(ub + kc * 32 + hi16 * 8);  // ds_read_b64
            acc0 = __builtin_amdgcn_mfma_f32_16x16x32_fp8_fp8((long)pa[0*16+kc], (long)bb, acc0, 0, 0, 0);
            acc1 = __builtin_amdgcn_mfma_f32_16x16x32_fp8_fp8((long)pa[1*16+kc], (long)bb, acc1, 0, 0, 0);
            acc2 = __builtin_amdgcn_mfma_f32_16x16x32_fp8_fp8((long)pa[2*16+kc], (long)bb, acc2, 0, 0, 0);
            acc3 = __builtin_amdgcn_mfma_f32_16x16x32_fp8_fp8((long)pa[3*16+kc], (long)bb, acc3, 0, 0, 0);
        }
        f32x4 sacc[4] = { acc0, acc1, acc2, acc3 };

        // e = exp(em + MiW) * s_raw  (no log, no max)
        loc = 0.f;
#pragma unroll
        for (int ti = 0; ti < 4; ++ti) {
#pragma unroll
            for (int r = 0; r < 4; ++r) {
                float e = __expf(em[ti][r] + MiW[ti][r]) * sacc[ti][r];
                e4[ti][r] = e; loc += e;
            }
        }
        loc += __shfl_xor(loc, 16);
        loc += __shfl_xor(loc, 32);
        if (l == 0) rB[w] = loc;
        K += CK + lS;                     // uses previous step's logS
        __syncthreads();                  // B1: rB ready
        S = rB[0];
#pragma unroll
        for (int j = 1; j < 8; ++j) S += rB[j];
        lS = __logf(S);
        if (tid == 0) out[(size_t)b * MM + t] = K + lS;
        sc = 64.f / S;
        if ((l & 15) == 0) {
#pragma unroll
            for (int ti = 0; ti < 4; ++ti) {
                int d = 0;
                d = __builtin_amdgcn_cvt_pk_fp8_f32(e4[ti][0] * sc, e4[ti][1] * sc, d, false);
                d = __builtin_amdgcn_cvt_pk_fp8_f32(e4[ti][2] * sc, e4[ti][3] * sc, d, true);
                *(u32*)&us8[t & 1][(w * 4 + ti) * 16 + r4] = (u32)d;
            }
        }
        __syncthreads();                  // B2: us8[t&1] ready for next step
    }
}

extern "C" void kernel_launch(void* const* d_in, const int* in_sizes, int n_in,
                              void* d_out, int out_size, void* d_ws, size_t ws_size,
                              hipStream_t stream) {
    const int*   obs = (const int*)d_in[0];
    const float* pri = (const float*)d_in[1];
    const float* T   = (const float*)d_in[2];
    const float* E   = (const float*)d_in[3];
    float* out = (float*)d_out;
    char* ws = (char*)d_ws;

    float* c   = (float*)(ws + 0);
    float* lp  = (float*)(ws + 2048);
    float* M   = (float*)(ws + 4096);
    u32*   PA  = (u32*)(ws + 8192);                       // 256 KB fp8 A-frags
    float* EtT = (float*)(ws + 8192 + 256 * 1024);        // 512 KB

    k_col_lse<<<8,   64, 0, stream>>>(T, c);
    k_priors <<<1,  512, 0, stream>>>(pri, lp);
    k_rowM   <<<512, 64, 0, stream>>>(T, c, M);
    k_packA  <<<512, 64, 0, stream>>>(T, c, M, PA);
    k_rowE   <<<512, 64, 0, stream>>>(E, EtT);
    k_scan   <<<BB, 512, 0, stream>>>(obs, lp, M, PA, EtT, out);
}